// Round 15
// baseline (479.070 us; speedup 1.0000x reference)
//
#include <hip/hip_runtime.h>
#include <cstdint>
#include <cstddef>

// ---------------------------------------------------------------------------
// GCN forward, MFMA edition:
//   bucketed graph preprocessing (NO scattered global atomics anywhere):
//     bcount -> bscan -> scatter2 -> bucket_dst (ind+rowp+csr) ->
//     bucket_src (outd in LDS + cs/cd/didx fused)
//   -> WF=projW@W1mid (+cb fused) -> WT frag-order hi/lo bf16 (fused)
//   -> h1 = cs*(x@W1+cb) [split-bf16 3-term MFMA] -> agg1 -> y=relu(...)
//   -> h2 = cs*(y@W2) -> agg2 -> out
// Split trick: a = a_hi + a_lo (bf16 trunc + bf16 residual);
// D = ahi*bhi + alo*bhi + ahi*blo -> only O(2^-17) rel. terms dropped.
// R14 lesson: 6 k_h1 variants pinned at ~110us / 1.0-1.2 TB/s effective
// while fill hits 7 TB/s -> the pin is the COLUMN-SLICED A address stream
// (128B per 2KB-strided row per step, 16 revisits/page), not scheduling.
// v7 fix: stage the block's WHOLE 32-row x 2KB features tile CONTIGUOUSLY
// (4KB/instruction) into 64KB static LDS (chunk-swizzle cc^=(row&7), derived
// conflict-free for linear writes AND frag reads), then a ZERO-BARRIER
// K-loop: A from LDS, B double-buffered in REGISTERS (full unroll -> static
// indexing, rule #20), dist-1 covered by the 48-MFMA step window. 2 blocks/
// CU -> load phase of one block overlaps compute of the other.
// R6/R7 lesson: scattered 4B atomics across XCD L2s = ~64B writeback each;
// bucket so each 1024-node range is built by ONE block in LDS.
// R4 lesson: never cap VGPRs below acc needs (spill -> scratch traffic).
// ---------------------------------------------------------------------------

typedef short short8 __attribute__((ext_vector_type(8)));
typedef float f32x4 __attribute__((ext_vector_type(4)));

__device__ __forceinline__ unsigned short f2bf(float f) {
    unsigned u = __float_as_uint(f);
    u += 0x7fff + ((u >> 16) & 1);   // RNE
    return (unsigned short)(u >> 16);
}
__device__ __forceinline__ float bf2f(unsigned short s) {
    return __uint_as_float(((unsigned)s) << 16);
}

__device__ __forceinline__ void split_f4(float4 a, float4 b, short8& hv, short8& lv) {
    float f[8] = {a.x, a.y, a.z, a.w, b.x, b.y, b.z, b.w};
#pragma unroll
    for (int i = 0; i < 8; ++i) {
        unsigned u = __float_as_uint(f[i]);
        hv[i] = (short)(u >> 16);
        float r = f[i] - __uint_as_float(u & 0xffff0000u);
        lv[i] = (short)(__float_as_uint(r) >> 16);
    }
}

// ---- bucket preprocessing (buckets = 1024-node ranges, nb <= 128) ----

__global__ __launch_bounds__(256) void k_bcount(
    const int* __restrict__ src, const int* __restrict__ dst, int E,
    int* __restrict__ dcount, int* __restrict__ scount)
{
    __shared__ int dh[128], sh_[128];
    int t = threadIdx.x;
    if (t < 128) { dh[t] = 0; sh_[t] = 0; }
    __syncthreads();
    int e0 = blockIdx.x * 4096;
#pragma unroll
    for (int i = 0; i < 16; ++i) {
        int idx = e0 + t + i * 256;
        if (idx < E) {
            atomicAdd(&dh[dst[idx] >> 10], 1);
            atomicAdd(&sh_[src[idx] >> 10], 1);
        }
    }
    __syncthreads();
    if (t < 128) {
        if (dh[t]) atomicAdd(&dcount[t], dh[t]);
        if (sh_[t]) atomicAdd(&scount[t], sh_[t]);
    }
}

__global__ __launch_bounds__(128) void k_bscan(
    const int* __restrict__ dcount, const int* __restrict__ scount, int nb,
    int E, int* __restrict__ dboff, int* __restrict__ sboff,
    int* __restrict__ dcur, int* __restrict__ scur,
    int* __restrict__ rowp, int N)
{
    __shared__ int sh[128];
    int t = threadIdx.x;
    int v = (t < nb) ? dcount[t] : 0;
    sh[t] = v;
    __syncthreads();
    for (int off = 1; off < 128; off <<= 1) {
        int x = (t >= off) ? sh[t - off] : 0;
        __syncthreads();
        sh[t] += x;
        __syncthreads();
    }
    if (t < nb) { int e = sh[t] - v; dboff[t] = e; dcur[t] = e; }
    __syncthreads();
    int v2 = (t < nb) ? scount[t] : 0;
    sh[t] = v2;
    __syncthreads();
    for (int off = 1; off < 128; off <<= 1) {
        int x = (t >= off) ? sh[t - off] : 0;
        __syncthreads();
        sh[t] += x;
        __syncthreads();
    }
    if (t < nb) { int e = sh[t] - v2; sboff[t] = e; scur[t] = e; }
    if (t == 0) rowp[N] = E;
}

__global__ __launch_bounds__(256) void k_scatter2(
    const int* __restrict__ src, const int* __restrict__ dst, int E,
    int* __restrict__ dcur, int* __restrict__ scur,
    unsigned* __restrict__ ebuf, unsigned short* __restrict__ sbuf, int nb)
{
    __shared__ int dh[128], dbase[128], sh_[128], sbase[128];
    int t = threadIdx.x;
    int e0 = blockIdx.x * 4096;
    if (t < 128) { dh[t] = 0; sh_[t] = 0; }
    __syncthreads();
    int s_[16], d_[16];
#pragma unroll
    for (int i = 0; i < 16; ++i) {
        int idx = e0 + t + i * 256;
        if (idx < E) {
            s_[i] = src[idx];
            d_[i] = dst[idx];
            atomicAdd(&dh[d_[i] >> 10], 1);
            atomicAdd(&sh_[s_[i] >> 10], 1);
        } else d_[i] = -1;
    }
    __syncthreads();
    if (t < nb) {
        if (dh[t]) dbase[t] = atomicAdd(&dcur[t], dh[t]);
        if (sh_[t]) sbase[t] = atomicAdd(&scur[t], sh_[t]);
    }
    __syncthreads();
    if (t < 128) { dh[t] = 0; sh_[t] = 0; }
    __syncthreads();
#pragma unroll
    for (int i = 0; i < 16; ++i) {
        if (d_[i] >= 0) {
            int b = d_[i] >> 10;
            int p = dbase[b] + atomicAdd(&dh[b], 1);
            ebuf[p] = (unsigned)s_[i] | ((unsigned)(d_[i] & 1023) << 17);
            int bs = s_[i] >> 10;
            int q = sbase[bs] + atomicAdd(&sh_[bs], 1);
            sbuf[q] = (unsigned short)(s_[i] & 1023);
        }
    }
}

__global__ __launch_bounds__(512) void k_bucket_dst(
    const unsigned* __restrict__ ebuf, const int* __restrict__ dboff,
    const int* __restrict__ dcount, int* __restrict__ ind,
    int* __restrict__ rowp, int* __restrict__ csr, int N)
{
    __shared__ int cnt[1024];
    __shared__ int sums[512];
    int b = blockIdx.x;
    int nb0 = b << 10;
    int ncnt = min(1024, N - nb0);
    int t = threadIdx.x;
    cnt[t] = 0; cnt[t + 512] = 0;
    __syncthreads();
    int lo = dboff[b], hi = lo + dcount[b];
    for (int idx = lo + t; idx < hi; idx += 512)
        atomicAdd(&cnt[ebuf[idx] >> 17], 1);
    __syncthreads();
    int c0 = cnt[2 * t], c1 = cnt[2 * t + 1];
    sums[t] = c0 + c1;
    __syncthreads();
    for (int off = 1; off < 512; off <<= 1) {
        int x = (t >= off) ? sums[t - off] : 0;
        __syncthreads();
        sums[t] += x;
        __syncthreads();
    }
    int excl = sums[t] - (c0 + c1);
    int r0 = lo + excl, r1 = r0 + c0;
    if (2 * t < ncnt)     { rowp[nb0 + 2 * t] = r0;     ind[nb0 + 2 * t] = c0; }
    if (2 * t + 1 < ncnt) { rowp[nb0 + 2 * t + 1] = r1; ind[nb0 + 2 * t + 1] = c1; }
    __syncthreads();
    cnt[2 * t] = r0; cnt[2 * t + 1] = r1;
    __syncthreads();
    for (int idx = lo + t; idx < hi; idx += 512) {
        unsigned e = ebuf[idx];
        int p = atomicAdd(&cnt[e >> 17], 1);
        csr[p] = (int)(e & 0x1FFFF);
    }
}

// one block per bucket: out-degree histogram in LDS, then cs/cd/didx fused.
__global__ __launch_bounds__(512) void k_bucket_src(
    const unsigned short* __restrict__ sbuf, const int* __restrict__ sboff,
    const int* __restrict__ scount, const int* __restrict__ ind,
    float* __restrict__ cs, float* __restrict__ cd, int* __restrict__ didx,
    int N)
{
    __shared__ int cnt[1024];
    int b = blockIdx.x;
    int nb0 = b << 10;
    int ncnt = min(1024, N - nb0);
    int t = threadIdx.x;
    cnt[t] = 0; cnt[t + 512] = 0;
    __syncthreads();
    int lo = sboff[b], hi = lo + scount[b];
    for (int idx = lo + t; idx < hi; idx += 512)
        atomicAdd(&cnt[sbuf[idx]], 1);
    __syncthreads();
#pragma unroll
    for (int k = 0; k < 2; ++k) {
        int loc = t + k * 512;
        if (loc < ncnt) {
            int od = cnt[loc];
            int id = ind[nb0 + loc];
            cs[nb0 + loc] = rsqrtf((float)(od > 0 ? od : 1));
            cd[nb0 + loc] = rsqrtf((float)(id > 0 ? id : 1));
            int d = od + id;
            didx[nb0 + loc] = d > 511 ? 511 : d;
        }
    }
}

// WF[k][j] = sum_m projW[k][m] * W1[64+m][j] (512x128 fp32); block 256 = cb
__global__ __launch_bounds__(256) void k_wf(
    const float* __restrict__ projW, const float* __restrict__ projb,
    const float* __restrict__ W1, float* __restrict__ WF,
    float* __restrict__ cb)
{
    if (blockIdx.x == 256) {
        int j = threadIdx.x;
        if (j < 128) {
            float s = 0.f;
            for (int m = 0; m < 128; ++m)
                s = fmaf(projb[m], W1[(size_t)(64 + m) * 128 + j], s);
            cb[j] = s;
        }
        return;
    }
    int idx = blockIdx.x * 256 + threadIdx.x;
    int k = idx >> 7, j = idx & 127;
    const float* a = projW + (size_t)k * 128;
    float s = 0.f;
#pragma unroll 8
    for (int m = 0; m < 128; ++m) s = fmaf(a[m], W1[(size_t)(64 + m) * 128 + j], s);
    WF[idx] = s;
}

// Fused weight-fragment kernel: idx<81920 -> layer1 wtf; else layer2 w2tf.
__global__ __launch_bounds__(256) void k_wt(
    const float* __restrict__ WF, const float* __restrict__ W1,
    const float* __restrict__ W2,
    unsigned short* __restrict__ wtf_hi, unsigned short* __restrict__ wtf_lo,
    unsigned short* __restrict__ w2tf_hi, unsigned short* __restrict__ w2tf_lo)
{
    int idx = blockIdx.x * 256 + threadIdx.x;   // 81920 + 8192 = 90112
    if (idx < 81920) {
        int e = idx & 7;
        int lane = (idx >> 3) & 63;
        int ci = (idx >> 9) & 7;
        int t = idx >> 12;
        int j = ci * 16 + (lane & 15);
        int k = t * 32 + (lane >> 4) * 8 + e;
        float v;
        if (k < 512) v = WF[(size_t)k * 128 + j];
        else if (k < 576) v = W1[(size_t)(k - 512) * 128 + j];
        else v = W1[(size_t)(192 + (k - 576)) * 128 + j];
        unsigned short h = f2bf(v);
        wtf_hi[idx] = h;
        float r = v - bf2f(h);
        wtf_lo[idx] = (unsigned short)(__float_as_uint(r) >> 16);
    } else if (idx < 90112) {
        int i2 = idx - 81920;
        int e = i2 & 7;
        int lane = (i2 >> 3) & 63;
        int ci = (i2 >> 9) & 3;
        int t = i2 >> 11;
        int j = ci * 16 + (lane & 15);
        int k = t * 32 + (lane >> 4) * 8 + e;
        float v = W2[(size_t)k * 64 + j];
        unsigned short h = f2bf(v);
        w2tf_hi[i2] = h;
        float r = v - bf2f(h);
        w2tf_lo[i2] = (unsigned short)(__float_as_uint(r) >> 16);
    }
}

// ---- k_h1 v7: 32-row blocks, 128 threads (2 waves x 16 rows x 128 cols).
// Phase 1: stage the block's 32x512-float features tile CONTIGUOUSLY into
// 64KB static LDS (chunk-swizzle cc ^= row&7 -> conflict-free both sides).
// Phase 2: zero-barrier K-loop; A from LDS, B double-buffered in registers
// (fully unrolled t -> static indexing), tail steps 16-19 from named regs.
__global__ __launch_bounds__(128, 1) void k_h1(
    const float* __restrict__ logits, const float* __restrict__ features,
    const float* __restrict__ deg_table, const int* __restrict__ didx,
    const unsigned short* __restrict__ wtf_hi, const unsigned short* __restrict__ wtf_lo,
    const float* __restrict__ cb, const float* __restrict__ cs,
    unsigned short* __restrict__ h1, int N)
{
    __shared__ __align__(16) float4 Asm4[4096];   // [row32][chunk128], 64 KB
    int tid = threadIdx.x;                        // 0..127
    int lane = tid & 63, w = tid >> 6;            // 2 waves
    int fr = lane & 15, kg = lane >> 4;
    int i0 = blockIdx.x * 32;
    int rrel = w * 16 + fr;                       // 0..31
    int r0 = i0 + rrel; if (r0 >= N) r0 = N - 1;
    int dd0 = didx[r0];

    // phase 1: contiguous stage (4 KB per instruction across the block)
    {
        const float4* gf = (const float4*)features;
        size_t gmax = (size_t)N * 128 - 1;
        for (int o = 0; o < 4; ++o) {
            float4 v[8];
#pragma unroll
            for (int c = 0; c < 8; ++c) {
                size_t gi = (size_t)i0 * 128 + tid + (o * 8 + c) * 128;
                if (gi > gmax) gi = gmax;
                v[c] = gf[gi];
            }
#pragma unroll
            for (int c = 0; c < 8; ++c) {
                int idx = tid + (o * 8 + c) * 128;
                int row = idx >> 7, cc = idx & 127;
                Asm4[row * 128 + (cc ^ (row & 7))] = v[c];
            }
        }
    }

    // tail-step A prefetch (logits k0..63, deg k0..63), named regs
    const float* lgp = logits + (size_t)r0 * 64 + kg * 8;
    const float* dgp = deg_table + (size_t)dd0 * 64 + kg * 8;
    float4 T0a = *(const float4*)(lgp);
    float4 T0b = *(const float4*)(lgp + 4);
    float4 T1a = *(const float4*)(lgp + 32);
    float4 T1b = *(const float4*)(lgp + 36);
    float4 T2a = *(const float4*)(dgp);
    float4 T2b = *(const float4*)(dgp + 4);
    float4 T3a = *(const float4*)(dgp + 32);
    float4 T3b = *(const float4*)(dgp + 36);

    f32x4 acc[8];
#pragma unroll
    for (int ci = 0; ci < 8; ++ci) acc[ci] = (f32x4)0.f;

    // B double-buffered in registers; t fully unrolled -> static indexing
    uint4 bh[2][8], bl[2][8];
#pragma unroll
    for (int ci = 0; ci < 8; ++ci) {
        bh[0][ci] = *(const uint4*)(wtf_hi + ((size_t)(0 * 8 + ci) * 64 + lane) * 8);
        bl[0][ci] = *(const uint4*)(wtf_lo + ((size_t)(0 * 8 + ci) * 64 + lane) * 8);
    }
    __syncthreads();   // LDS A ready (and B(0) regs)

#pragma unroll
    for (int t = 0; t < 20; ++t) {
        const int s = t & 1;
        if (t + 1 < 20) {
#pragma unroll
            for (int ci = 0; ci < 8; ++ci) {
                bh[s ^ 1][ci] = *(const uint4*)(wtf_hi + ((size_t)((t + 1) * 8 + ci) * 64 + lane) * 8);
                bl[s ^ 1][ci] = *(const uint4*)(wtf_lo + ((size_t)((t + 1) * 8 + ci) * 64 + lane) * 8);
            }
        }
        short8 ah, al;
        if (t < 16) {
            int c0 = t * 8 + kg * 2;
            float4 f0 = Asm4[rrel * 128 + ((c0    ) ^ (rrel & 7))];
            float4 f1 = Asm4[rrel * 128 + ((c0 + 1) ^ (rrel & 7))];
            split_f4(f0, f1, ah, al);
        } else if (t == 16) split_f4(T0a, T0b, ah, al);
        else if (t == 17) split_f4(T1a, T1b, ah, al);
        else if (t == 18) split_f4(T2a, T2b, ah, al);
        else              split_f4(T3a, T3b, ah, al);
#pragma unroll
        for (int ci = 0; ci < 8; ++ci) {
            short8 bhv = *(short8*)&bh[s][ci];
            short8 blv = *(short8*)&bl[s][ci];
            acc[ci] = __builtin_amdgcn_mfma_f32_16x16x32_bf16(ah, bhv, acc[ci], 0, 0, 0);
            acc[ci] = __builtin_amdgcn_mfma_f32_16x16x32_bf16(al, bhv, acc[ci], 0, 0, 0);
            acc[ci] = __builtin_amdgcn_mfma_f32_16x16x32_bf16(ah, blv, acc[ci], 0, 0, 0);
        }
    }

    // C/D layout: col = ci*16 + fr, row = i0 + w*16 + kg*4 + j  [m89]
    float cbv[8];
#pragma unroll
    for (int ci = 0; ci < 8; ++ci) cbv[ci] = cb[ci * 16 + fr];
#pragma unroll
    for (int j = 0; j < 4; ++j) {
        int row = i0 + w * 16 + kg * 4 + j;
        if (row < N) {
            float scv = cs[row];
#pragma unroll
            for (int ci = 0; ci < 8; ++ci) {
                h1[(size_t)row * 128 + ci * 16 + fr] =
                    f2bf(scv * (acc[ci][j] + cbv[ci]));
            }
        }
    }
}

// Layer-1 aggregation: 32-lane half-wave per node, uint2 gathers, unroll 8.
__global__ __launch_bounds__(256) void k_agg1(
    const unsigned short* __restrict__ h1, const int* __restrict__ rowp,
    const int* __restrict__ csr, const float* __restrict__ cd,
    const float* __restrict__ b1, float* __restrict__ y, int N)
{
    int i = blockIdx.x * 8 + (threadIdx.x >> 5);
    if (i >= N) return;
    int lane = threadIdx.x & 31;
    int s0 = rowp[i], s1 = rowp[i + 1];
    float a0 = 0.f, a1 = 0.f, a2 = 0.f, a3 = 0.f;
    int e = s0;
    for (; e + 8 <= s1; e += 8) {
        uint2 v0 = *(const uint2*)(h1 + (size_t)csr[e + 0] * 128 + lane * 4);
        uint2 v1 = *(const uint2*)(h1 + (size_t)csr[e + 1] * 128 + lane * 4);
        uint2 v2 = *(const uint2*)(h1 + (size_t)csr[e + 2] * 128 + lane * 4);
        uint2 v3 = *(const uint2*)(h1 + (size_t)csr[e + 3] * 128 + lane * 4);
        uint2 v4 = *(const uint2*)(h1 + (size_t)csr[e + 4] * 128 + lane * 4);
        uint2 v5 = *(const uint2*)(h1 + (size_t)csr[e + 5] * 128 + lane * 4);
        uint2 v6 = *(const uint2*)(h1 + (size_t)csr[e + 6] * 128 + lane * 4);
        uint2 v7 = *(const uint2*)(h1 + (size_t)csr[e + 7] * 128 + lane * 4);
        a0 += ((__uint_as_float(v0.x << 16) + __uint_as_float(v1.x << 16)) +
               (__uint_as_float(v2.x << 16) + __uint_as_float(v3.x << 16))) +
              ((__uint_as_float(v4.x << 16) + __uint_as_float(v5.x << 16)) +
               (__uint_as_float(v6.x << 16) + __uint_as_float(v7.x << 16)));
        a1 += ((__uint_as_float(v0.x & 0xffff0000u) + __uint_as_float(v1.x & 0xffff0000u)) +
               (__uint_as_float(v2.x & 0xffff0000u) + __uint_as_float(v3.x & 0xffff0000u))) +
              ((__uint_as_float(v4.x & 0xffff0000u) + __uint_as_float(v5.x & 0xffff0000u)) +
               (__uint_as_float(v6.x & 0xffff0000u) + __uint_as_float(v7.x & 0xffff0000u)));
        a2 += ((__uint_as_float(v0.y << 16) + __uint_as_float(v1.y << 16)) +
               (__uint_as_float(v2.y << 16) + __uint_as_float(v3.y << 16))) +
              ((__uint_as_float(v4.y << 16) + __uint_as_float(v5.y << 16)) +
               (__uint_as_float(v6.y << 16) + __uint_as_float(v7.y << 16)));
        a3 += ((__uint_as_float(v0.y & 0xffff0000u) + __uint_as_float(v1.y & 0xffff0000u)) +
               (__uint_as_float(v2.y & 0xffff0000u) + __uint_as_float(v3.y & 0xffff0000u))) +
              ((__uint_as_float(v4.y & 0xffff0000u) + __uint_as_float(v5.y & 0xffff0000u)) +
               (__uint_as_float(v6.y & 0xffff0000u) + __uint_as_float(v7.y & 0xffff0000u)));
    }
    for (; e < s1; ++e) {
        uint2 v = *(const uint2*)(h1 + (size_t)csr[e] * 128 + lane * 4);
        a0 += __uint_as_float(v.x << 16);
        a1 += __uint_as_float(v.x & 0xffff0000u);
        a2 += __uint_as_float(v.y << 16);
        a3 += __uint_as_float(v.y & 0xffff0000u);
    }
    float cdi = cd[i];
    float4 bv = *(const float4*)(b1 + lane * 4);
    float4 o;
    o.x = fmaxf(fmaf(a0, cdi, bv.x), 0.f);
    o.y = fmaxf(fmaf(a1, cdi, bv.y), 0.f);
    o.z = fmaxf(fmaf(a2, cdi, bv.z), 0.f);
    o.w = fmaxf(fmaf(a3, cdi, bv.w), 0.f);
    *(float4*)(y + (size_t)i * 128 + lane * 4) = o;
}

// ---- k_h2 (unchanged): A direct; fragment-order B2 (32KB) staged once.
__global__ __launch_bounds__(256, 3) void k_h2(
    const float* __restrict__ y,
    const unsigned short* __restrict__ w2tf_hi, const unsigned short* __restrict__ w2tf_lo,
    const float* __restrict__ cs, unsigned short* __restrict__ h2, int N)
{
    constexpr int NT = 4;
    __shared__ __align__(16) short B2h[8192];
    __shared__ __align__(16) short B2l[8192];
    int tid = threadIdx.x;
    int lane = tid & 63, w = tid >> 6;
    int fr = lane & 15, kg = lane >> 4;
    int i0 = blockIdx.x * 128 + w * 32;
    int r0 = i0 + fr;       if (r0 >= N) r0 = N - 1;
    int r1 = i0 + 16 + fr;  if (r1 >= N) r1 = N - 1;
    const float* a0 = y + (size_t)r0 * 128 + kg * 8;
    const float* a1 = y + (size_t)r1 * 128 + kg * 8;

#pragma unroll
    for (int i = 0; i < 4; ++i) {
        *(uint4*)&B2h[(i * 256 + tid) * 8] = *(const uint4*)(w2tf_hi + (size_t)(i * 256 + tid) * 8);
        *(uint4*)&B2l[(i * 256 + tid) * 8] = *(const uint4*)(w2tf_lo + (size_t)(i * 256 + tid) * 8);
    }
    __syncthreads();

    f32x4 acc[2][4];
#pragma unroll
    for (int ri = 0; ri < 2; ++ri)
#pragma unroll
        for (int ci = 0; ci < 4; ++ci) acc[ri][ci] = (f32x4)0.f;

    float4 ar00 = *(const float4*)(a0);
    float4 ar01 = *(const float4*)(a0 + 4);
    float4 ar10 = *(const float4*)(a1);
    float4 ar11 = *(const float4*)(a1 + 4);

    for (int t = 0; t < NT; ++t) {
        short8 ah0, al0, ah1, al1;
        split_f4(ar00, ar01, ah0, al0);
        split_f4(ar10, ar11, ah1, al1);
        if (t + 1 < NT) {
            ar00 = *(const float4*)(a0 + (t + 1) * 32);
            ar01 = *(const float4*)(a0 + (t + 1) * 32 + 4);
            ar10 = *(const float4*)(a1 + (t + 1) * 32);
            ar11 = *(const float4*)(a1 + (t + 1) * 32 + 4);
        }
#pragma unroll
        for (int ci = 0; ci < 4; ++ci) {
            short8 bh = *(const short8*)&B2h[((t * 4 + ci) * 64 + lane) * 8];
            short8 bl = *(const short8*)&B2l[((t * 4 + ci) * 64 + lane) * 8];
            acc[0][ci] = __builtin_amdgcn_mfma_f32_16x16x32_bf16(ah0, bh, acc[0][ci], 0, 0, 0);
            acc[0][ci] = __builtin_amdgcn_mfma_f32_16x16x32_bf16(al0, bh, acc[0][ci], 0, 0, 0);
            acc[0][ci] = __builtin_amdgcn_mfma_f32_16x16x32_bf16(ah0, bl, acc[0][ci], 0, 0, 0);
            acc[1][ci] = __builtin_amdgcn_mfma_f32_16x16x32_bf16(ah1, bh, acc[1][ci], 0, 0, 0);
            acc[1][ci] = __builtin_amdgcn_mfma_f32_16x16x32_bf16(al1, bh, acc[1][ci], 0, 0, 0);
            acc[1][ci] = __builtin_amdgcn_mfma_f32_16x16x32_bf16(ah1, bl, acc[1][ci], 0, 0, 0);
        }
    }

#pragma unroll
    for (int ri = 0; ri < 2; ++ri) {
#pragma unroll
        for (int j = 0; j < 4; ++j) {
            int row = i0 + ri * 16 + kg * 4 + j;
            if (row < N) {
                float scv = cs[row];
#pragma unroll
                for (int ci = 0; ci < 4; ++ci) {
                    h2[(size_t)row * 64 + ci * 16 + fr] = f2bf(scv * acc[ri][ci][j]);
                }
            }
        }
    }
}

// Layer-2 aggregation: out[i] = (sum h2[src_e]) * cd[i] + b2
__global__ __launch_bounds__(256) void k_agg2(
    const unsigned short* __restrict__ h2, const int* __restrict__ rowp,
    const int* __restrict__ csr, const float* __restrict__ cd,
    const float* __restrict__ b2, float* __restrict__ out, int N)
{
    int i = blockIdx.x * 8 + (threadIdx.x >> 5);
    if (i >= N) return;
    int lane = threadIdx.x & 31;
    int s0 = rowp[i], s1 = rowp[i + 1];
    float ax = 0.f, ay = 0.f;
    int e = s0;
    for (; e + 8 <= s1; e += 8) {
        unsigned u0 = *(const unsigned*)(h2 + (size_t)csr[e + 0] * 64 + lane * 2);
        unsigned u1 = *(const unsigned*)(h2 + (size_t)csr[e + 1] * 64 + lane * 2);
        unsigned u2 = *(const unsigned*)(h2 + (size_t)csr[e + 2] * 64 + lane * 2);
        unsigned u3 = *(const unsigned*)(h2 + (size_t)csr[e + 3] * 64 + lane * 2);
        unsigned u4 = *(const unsigned*)(h2 + (size_t)csr[e + 4] * 64 + lane * 2);
        unsigned u5 = *(const unsigned*)(h2 + (size_t)csr[e + 5] * 64 + lane * 2);
        unsigned u6 = *(const unsigned*)(h2 + (size_t)csr[e + 6] * 64 + lane * 2);
        unsigned u7 = *(const unsigned*)(h2 + (size_t)csr[e + 7] * 64 + lane * 2);
        ax += ((__uint_as_float(u0 << 16) + __uint_as_float(u1 << 16)) +
               (__uint_as_float(u2 << 16) + __uint_as_float(u3 << 16))) +
              ((__uint_as_float(u4 << 16) + __uint_as_float(u5 << 16)) +
               (__uint_as_float(u6 << 16) + __uint_as_float(u7 << 16)));
        ay += ((__uint_as_float(u0 & 0xffff0000u) + __uint_as_float(u1 & 0xffff0000u)) +
               (__uint_as_float(u2 & 0xffff0000u) + __uint_as_float(u3 & 0xffff0000u))) +
              ((__uint_as_float(u4 & 0xffff0000u) + __uint_as_float(u5 & 0xffff0000u)) +
               (__uint_as_float(u6 & 0xffff0000u) + __uint_as_float(u7 & 0xffff0000u)));
    }
    for (; e < s1; ++e) {
        unsigned u = *(const unsigned*)(h2 + (size_t)csr[e] * 64 + lane * 2);
        ax += __uint_as_float(u << 16);
        ay += __uint_as_float(u & 0xffff0000u);
    }
    float cdi = cd[i];
    float2 o;
    o.x = fmaf(ax, cdi, b2[lane * 2 + 0]);
    o.y = fmaf(ay, cdi, b2[lane * 2 + 1]);
    *(float2*)(out + (size_t)i * 64 + lane * 2) = o;
}

extern "C" void kernel_launch(void* const* d_in, const int* in_sizes, int n_in,
                              void* d_out, int out_size, void* d_ws, size_t ws_size,
                              hipStream_t stream)
{
    const int* src = (const int*)d_in[0];
    const int* dst = (const int*)d_in[1];
    const float* logits = (const float*)d_in[2];
    const float* features = (const float*)d_in[3];
    const float* projW = (const float*)d_in[4];
    const float* projb = (const float*)d_in[5];
    const float* deg_table = (const float*)d_in[6];
    const float* W1 = (const float*)d_in[7];
    const float* b1 = (const float*)d_in[8];
    const float* W2 = (const float*)d_in[9];
    const float* b2 = (const float*)d_in[10];
    const int E = in_sizes[0];
    const int N = in_sizes[2] / 64;

    char* base = (char*)d_ws;
    size_t off = 0;
    auto alloc = [&](size_t bytes) -> void* {
        void* p = base + off;
        off += (bytes + 255) & ~(size_t)255;
        return p;
    };
    int* ind    = (int*)alloc((size_t)N * 4);
    int* rowp   = (int*)alloc((size_t)(N + 1) * 4);
    int* csr    = (int*)alloc((size_t)E * 4);
    unsigned* ebuf = (unsigned*)alloc((size_t)E * 4);
    unsigned short* sbuf = (unsigned short*)alloc((size_t)E * 2);
    int* didx   = (int*)alloc((size_t)N * 4);
    float* cs   = (float*)alloc((size_t)N * 4);
    float* cd   = (float*)alloc((size_t)N * 4);
    float* WF   = (float*)alloc((size_t)512 * 128 * 4);
    float* cb   = (float*)alloc((size_t)128 * 4);
    int* dcount = (int*)alloc(128 * 4);
    int* scount = (int*)alloc(128 * 4);
    int* dboff  = (int*)alloc(128 * 4);
    int* sboff  = (int*)alloc(128 * 4);
    int* dcur   = (int*)alloc(128 * 4);
    int* scur   = (int*)alloc(128 * 4);
    unsigned short* wtf_hi  = (unsigned short*)alloc((size_t)81920 * 2);
    unsigned short* wtf_lo  = (unsigned short*)alloc((size_t)81920 * 2);
    unsigned short* w2tf_hi = (unsigned short*)alloc((size_t)8192 * 2);
    unsigned short* w2tf_lo = (unsigned short*)alloc((size_t)8192 * 2);
    unsigned short* h1 = (unsigned short*)alloc((size_t)N * 128 * 2);
    float* yb   = (float*)alloc((size_t)N * 128 * 4);
    unsigned short* h2 = h1;   // h1 dead after k_agg1; reuse
    float* outp = (float*)d_out;

    hipMemsetAsync(dcount, 0, 128 * 4, stream);
    hipMemsetAsync(scount, 0, 128 * 4, stream);

    int mb1 = (N + 31) / 32;     // 32-row k_h1 blocks
    int mb2 = (N + 127) / 128;   // 128-row k_h2 blocks
    int ebk = (E + 4095) / 4096;
    int nbuck = (N + 1023) / 1024;   // <=128 for N<=131072

    k_bcount<<<ebk, 256, 0, stream>>>(src, dst, E, dcount, scount);
    k_bscan<<<1, 128, 0, stream>>>(dcount, scount, nbuck, E, dboff, sboff, dcur, scur, rowp, N);
    k_scatter2<<<ebk, 256, 0, stream>>>(src, dst, E, dcur, scur, ebuf, sbuf, nbuck);
    k_bucket_dst<<<nbuck, 512, 0, stream>>>(ebuf, dboff, dcount, ind, rowp, csr, N);
    k_bucket_src<<<nbuck, 512, 0, stream>>>(sbuf, sboff, scount, ind, cs, cd, didx, N);
    k_wf<<<257, 256, 0, stream>>>(projW, projb, W1, WF, cb);
    k_wt<<<352, 256, 0, stream>>>(WF, W1, W2, wtf_hi, wtf_lo, w2tf_hi, w2tf_lo);
    k_h1<<<mb1, 128, 0, stream>>>(logits, features, deg_table, didx, wtf_hi, wtf_lo, cb, cs, h1, N);
    k_agg1<<<(N + 7) / 8, 256, 0, stream>>>(h1, rowp, csr, cd, b1, yb, N);
    k_h2<<<mb2, 256, 0, stream>>>(yb, w2tf_hi, w2tf_lo, cs, h2, N);
    k_agg2<<<(N + 7) / 8, 256, 0, stream>>>(h2, rowp, csr, cd, b2, outp, N);
}

// Round 16
// 304.967 us; speedup vs baseline: 1.5709x; 1.5709x over previous
//
#include <hip/hip_runtime.h>
#include <cstdint>
#include <cstddef>

// ---------------------------------------------------------------------------
// GCN forward, MFMA edition (R16 = R14 revert + narrower agg lane groups):
//   bucketed graph preprocessing (NO scattered global atomics anywhere):
//     bcount -> bscan -> scatter2 -> bucket_dst (ind+rowp+csr) ->
//     bucket_src (outd in LDS + cs/cd/didx fused)
//   -> WF=projW@W1mid (+cb fused) -> WT frag-order hi/lo bf16 (fused)
//   -> h1 = cs*(x@W1+cb) [split-bf16 3-term MFMA] -> agg1 -> y=relu(...)
//   -> h2 = cs*(y@W2) -> agg2 -> out
// Split trick: a = a_hi + a_lo (bf16 trunc + bf16 residual);
// D = ahi*bhi + alo*bhi + ahi*blo -> only O(2^-17) rel. terms dropped.
// R15 lesson (7th k_h1 variant, whole-row LDS staging: 285us, 11% occ):
// k_h1 ~110us IS the practical floor here — the column-sliced A stream
// (128B per 2KB-strided row, ~1 TB/s effective) pins it; frozen at the
// R14 form (64-row blocks, grid 1563, B frag-order LDS dbuf, dist-1).
// R13->R14 trend: narrower per-node lane groups help latency-bound gathers
// (more nodes in flight/wave) -> agg1 now 16-lane/node uint4, agg2 16-lane
// uint2 (same bytes/edge, 1/4 the load instrs, 4 nodes per wave).
// R6/R7 lesson: scattered 4B atomics across XCD L2s = ~64B writeback each;
// bucket so each 1024-node range is built by ONE block in LDS.
// R4 lesson: never cap VGPRs below acc needs (spill -> scratch traffic).
// ---------------------------------------------------------------------------

typedef short short8 __attribute__((ext_vector_type(8)));
typedef float f32x4 __attribute__((ext_vector_type(4)));

__device__ __forceinline__ unsigned short f2bf(float f) {
    unsigned u = __float_as_uint(f);
    u += 0x7fff + ((u >> 16) & 1);   // RNE
    return (unsigned short)(u >> 16);
}
__device__ __forceinline__ float bf2f(unsigned short s) {
    return __uint_as_float(((unsigned)s) << 16);
}

__device__ __forceinline__ void split_f4(float4 a, float4 b, short8& hv, short8& lv) {
    float f[8] = {a.x, a.y, a.z, a.w, b.x, b.y, b.z, b.w};
#pragma unroll
    for (int i = 0; i < 8; ++i) {
        unsigned u = __float_as_uint(f[i]);
        hv[i] = (short)(u >> 16);
        float r = f[i] - __uint_as_float(u & 0xffff0000u);
        lv[i] = (short)(__float_as_uint(r) >> 16);
    }
}

// ---- bucket preprocessing (buckets = 1024-node ranges, nb <= 128) ----

__global__ __launch_bounds__(256) void k_bcount(
    const int* __restrict__ src, const int* __restrict__ dst, int E,
    int* __restrict__ dcount, int* __restrict__ scount)
{
    __shared__ int dh[128], sh_[128];
    int t = threadIdx.x;
    if (t < 128) { dh[t] = 0; sh_[t] = 0; }
    __syncthreads();
    int e0 = blockIdx.x * 4096;
#pragma unroll
    for (int i = 0; i < 16; ++i) {
        int idx = e0 + t + i * 256;
        if (idx < E) {
            atomicAdd(&dh[dst[idx] >> 10], 1);
            atomicAdd(&sh_[src[idx] >> 10], 1);
        }
    }
    __syncthreads();
    if (t < 128) {
        if (dh[t]) atomicAdd(&dcount[t], dh[t]);
        if (sh_[t]) atomicAdd(&scount[t], sh_[t]);
    }
}

__global__ __launch_bounds__(128) void k_bscan(
    const int* __restrict__ dcount, const int* __restrict__ scount, int nb,
    int E, int* __restrict__ dboff, int* __restrict__ sboff,
    int* __restrict__ dcur, int* __restrict__ scur,
    int* __restrict__ rowp, int N)
{
    __shared__ int sh[128];
    int t = threadIdx.x;
    int v = (t < nb) ? dcount[t] : 0;
    sh[t] = v;
    __syncthreads();
    for (int off = 1; off < 128; off <<= 1) {
        int x = (t >= off) ? sh[t - off] : 0;
        __syncthreads();
        sh[t] += x;
        __syncthreads();
    }
    if (t < nb) { int e = sh[t] - v; dboff[t] = e; dcur[t] = e; }
    __syncthreads();
    int v2 = (t < nb) ? scount[t] : 0;
    sh[t] = v2;
    __syncthreads();
    for (int off = 1; off < 128; off <<= 1) {
        int x = (t >= off) ? sh[t - off] : 0;
        __syncthreads();
        sh[t] += x;
        __syncthreads();
    }
    if (t < nb) { int e = sh[t] - v2; sboff[t] = e; scur[t] = e; }
    if (t == 0) rowp[N] = E;
}

__global__ __launch_bounds__(256) void k_scatter2(
    const int* __restrict__ src, const int* __restrict__ dst, int E,
    int* __restrict__ dcur, int* __restrict__ scur,
    unsigned* __restrict__ ebuf, unsigned short* __restrict__ sbuf, int nb)
{
    __shared__ int dh[128], dbase[128], sh_[128], sbase[128];
    int t = threadIdx.x;
    int e0 = blockIdx.x * 4096;
    if (t < 128) { dh[t] = 0; sh_[t] = 0; }
    __syncthreads();
    int s_[16], d_[16];
#pragma unroll
    for (int i = 0; i < 16; ++i) {
        int idx = e0 + t + i * 256;
        if (idx < E) {
            s_[i] = src[idx];
            d_[i] = dst[idx];
            atomicAdd(&dh[d_[i] >> 10], 1);
            atomicAdd(&sh_[s_[i] >> 10], 1);
        } else d_[i] = -1;
    }
    __syncthreads();
    if (t < nb) {
        if (dh[t]) dbase[t] = atomicAdd(&dcur[t], dh[t]);
        if (sh_[t]) sbase[t] = atomicAdd(&scur[t], sh_[t]);
    }
    __syncthreads();
    if (t < 128) { dh[t] = 0; sh_[t] = 0; }
    __syncthreads();
#pragma unroll
    for (int i = 0; i < 16; ++i) {
        if (d_[i] >= 0) {
            int b = d_[i] >> 10;
            int p = dbase[b] + atomicAdd(&dh[b], 1);
            ebuf[p] = (unsigned)s_[i] | ((unsigned)(d_[i] & 1023) << 17);
            int bs = s_[i] >> 10;
            int q = sbase[bs] + atomicAdd(&sh_[bs], 1);
            sbuf[q] = (unsigned short)(s_[i] & 1023);
        }
    }
}

__global__ __launch_bounds__(512) void k_bucket_dst(
    const unsigned* __restrict__ ebuf, const int* __restrict__ dboff,
    const int* __restrict__ dcount, int* __restrict__ ind,
    int* __restrict__ rowp, int* __restrict__ csr, int N)
{
    __shared__ int cnt[1024];
    __shared__ int sums[512];
    int b = blockIdx.x;
    int nb0 = b << 10;
    int ncnt = min(1024, N - nb0);
    int t = threadIdx.x;
    cnt[t] = 0; cnt[t + 512] = 0;
    __syncthreads();
    int lo = dboff[b], hi = lo + dcount[b];
    for (int idx = lo + t; idx < hi; idx += 512)
        atomicAdd(&cnt[ebuf[idx] >> 17], 1);
    __syncthreads();
    int c0 = cnt[2 * t], c1 = cnt[2 * t + 1];
    sums[t] = c0 + c1;
    __syncthreads();
    for (int off = 1; off < 512; off <<= 1) {
        int x = (t >= off) ? sums[t - off] : 0;
        __syncthreads();
        sums[t] += x;
        __syncthreads();
    }
    int excl = sums[t] - (c0 + c1);
    int r0 = lo + excl, r1 = r0 + c0;
    if (2 * t < ncnt)     { rowp[nb0 + 2 * t] = r0;     ind[nb0 + 2 * t] = c0; }
    if (2 * t + 1 < ncnt) { rowp[nb0 + 2 * t + 1] = r1; ind[nb0 + 2 * t + 1] = c1; }
    __syncthreads();
    cnt[2 * t] = r0; cnt[2 * t + 1] = r1;
    __syncthreads();
    for (int idx = lo + t; idx < hi; idx += 512) {
        unsigned e = ebuf[idx];
        int p = atomicAdd(&cnt[e >> 17], 1);
        csr[p] = (int)(e & 0x1FFFF);
    }
}

// one block per bucket: out-degree histogram in LDS, then cs/cd/didx fused.
__global__ __launch_bounds__(512) void k_bucket_src(
    const unsigned short* __restrict__ sbuf, const int* __restrict__ sboff,
    const int* __restrict__ scount, const int* __restrict__ ind,
    float* __restrict__ cs, float* __restrict__ cd, int* __restrict__ didx,
    int N)
{
    __shared__ int cnt[1024];
    int b = blockIdx.x;
    int nb0 = b << 10;
    int ncnt = min(1024, N - nb0);
    int t = threadIdx.x;
    cnt[t] = 0; cnt[t + 512] = 0;
    __syncthreads();
    int lo = sboff[b], hi = lo + scount[b];
    for (int idx = lo + t; idx < hi; idx += 512)
        atomicAdd(&cnt[sbuf[idx]], 1);
    __syncthreads();
#pragma unroll
    for (int k = 0; k < 2; ++k) {
        int loc = t + k * 512;
        if (loc < ncnt) {
            int od = cnt[loc];
            int id = ind[nb0 + loc];
            cs[nb0 + loc] = rsqrtf((float)(od > 0 ? od : 1));
            cd[nb0 + loc] = rsqrtf((float)(id > 0 ? id : 1));
            int d = od + id;
            didx[nb0 + loc] = d > 511 ? 511 : d;
        }
    }
}

// WF[k][j] = sum_m projW[k][m] * W1[64+m][j] (512x128 fp32); block 256 = cb
__global__ __launch_bounds__(256) void k_wf(
    const float* __restrict__ projW, const float* __restrict__ projb,
    const float* __restrict__ W1, float* __restrict__ WF,
    float* __restrict__ cb)
{
    if (blockIdx.x == 256) {
        int j = threadIdx.x;
        if (j < 128) {
            float s = 0.f;
            for (int m = 0; m < 128; ++m)
                s = fmaf(projb[m], W1[(size_t)(64 + m) * 128 + j], s);
            cb[j] = s;
        }
        return;
    }
    int idx = blockIdx.x * 256 + threadIdx.x;
    int k = idx >> 7, j = idx & 127;
    const float* a = projW + (size_t)k * 128;
    float s = 0.f;
#pragma unroll 8
    for (int m = 0; m < 128; ++m) s = fmaf(a[m], W1[(size_t)(64 + m) * 128 + j], s);
    WF[idx] = s;
}

// Fused weight-fragment kernel: idx<81920 -> layer1 wtf; else layer2 w2tf.
__global__ __launch_bounds__(256) void k_wt(
    const float* __restrict__ WF, const float* __restrict__ W1,
    const float* __restrict__ W2,
    unsigned short* __restrict__ wtf_hi, unsigned short* __restrict__ wtf_lo,
    unsigned short* __restrict__ w2tf_hi, unsigned short* __restrict__ w2tf_lo)
{
    int idx = blockIdx.x * 256 + threadIdx.x;   // 81920 + 8192 = 90112
    if (idx < 81920) {
        int e = idx & 7;
        int lane = (idx >> 3) & 63;
        int ci = (idx >> 9) & 7;
        int t = idx >> 12;
        int j = ci * 16 + (lane & 15);
        int k = t * 32 + (lane >> 4) * 8 + e;
        float v;
        if (k < 512) v = WF[(size_t)k * 128 + j];
        else if (k < 576) v = W1[(size_t)(k - 512) * 128 + j];
        else v = W1[(size_t)(192 + (k - 576)) * 128 + j];
        unsigned short h = f2bf(v);
        wtf_hi[idx] = h;
        float r = v - bf2f(h);
        wtf_lo[idx] = (unsigned short)(__float_as_uint(r) >> 16);
    } else if (idx < 90112) {
        int i2 = idx - 81920;
        int e = i2 & 7;
        int lane = (i2 >> 3) & 63;
        int ci = (i2 >> 9) & 3;
        int t = i2 >> 11;
        int j = ci * 16 + (lane & 15);
        int k = t * 32 + (lane >> 4) * 8 + e;
        float v = W2[(size_t)k * 64 + j];
        unsigned short h = f2bf(v);
        w2tf_hi[i2] = h;
        float r = v - bf2f(h);
        w2tf_lo[i2] = (unsigned short)(__float_as_uint(r) >> 16);
    }
}

// ---- k_h1 (R14 version, frozen): 64-row blocks (4 waves x 16 rows), A
// direct-from-global dist-1 reg prefetch, B frag-order LDS double-buffer.
__global__ __launch_bounds__(256, 4) void k_h1(
    const float* __restrict__ logits, const float* __restrict__ features,
    const float* __restrict__ deg_table, const int* __restrict__ didx,
    const unsigned short* __restrict__ wtf_hi, const unsigned short* __restrict__ wtf_lo,
    const float* __restrict__ cb, const float* __restrict__ cs,
    unsigned short* __restrict__ h1, int N)
{
    constexpr int NT = 20;
    __shared__ __align__(16) short Bh[2][4096];
    __shared__ __align__(16) short Bl[2][4096];
    int tid = threadIdx.x;
    int lane = tid & 63, w = tid >> 6;
    int fr = lane & 15, kg = lane >> 4;
    int i0 = blockIdx.x * 64 + w * 16;
    int r0 = i0 + fr;  if (r0 >= N) r0 = N - 1;
    int dd0 = didx[r0];

    f32x4 acc[8];
#pragma unroll
    for (int ci = 0; ci < 8; ++ci) acc[ci] = (f32x4)0.f;

    auto aptr = [&](int t) -> const float* {
        if (t < 16) return features  + (size_t)r0 * 512 + t * 32 + kg * 8;
        if (t < 18) return logits    + (size_t)r0 * 64 + (t - 16) * 32 + kg * 8;
        return deg_table + (size_t)dd0 * 64 + (t - 18) * 32 + kg * 8;
    };

    float4 ac0, ac1, an0, an1;
    uint4 sbh0, sbh1, sbl0, sbl1;

    {
        const unsigned short* g = wtf_hi + tid * 8;
        sbh0 = *(const uint4*)g;
        sbh1 = *(const uint4*)(g + 2048);
        const unsigned short* g2 = wtf_lo + tid * 8;
        sbl0 = *(const uint4*)g2;
        sbl1 = *(const uint4*)(g2 + 2048);
        *(uint4*)&Bh[0][tid * 8] = sbh0;
        *(uint4*)&Bh[0][2048 + tid * 8] = sbh1;
        *(uint4*)&Bl[0][tid * 8] = sbl0;
        *(uint4*)&Bl[0][2048 + tid * 8] = sbl1;
        const float* p = aptr(0);
        ac0 = *(const float4*)p;  ac1 = *(const float4*)(p + 4);
    }
    __syncthreads();

    for (int t = 0; t < NT; ++t) {
        int cbuf = t & 1;
        if (t + 1 < NT) {
            const unsigned short* g = wtf_hi + (size_t)(t + 1) * 4096 + tid * 8;
            sbh0 = *(const uint4*)g;
            sbh1 = *(const uint4*)(g + 2048);
            const unsigned short* g2 = wtf_lo + (size_t)(t + 1) * 4096 + tid * 8;
            sbl0 = *(const uint4*)g2;
            sbl1 = *(const uint4*)(g2 + 2048);
            const float* p = aptr(t + 1);
            an0 = *(const float4*)p;  an1 = *(const float4*)(p + 4);
        }
        short8 ah, al;
        split_f4(ac0, ac1, ah, al);
#pragma unroll
        for (int ci = 0; ci < 8; ++ci) {
            short8 bh = *(const short8*)&Bh[cbuf][ci * 512 + lane * 8];
            short8 bl = *(const short8*)&Bl[cbuf][ci * 512 + lane * 8];
            acc[ci] = __builtin_amdgcn_mfma_f32_16x16x32_bf16(ah, bh, acc[ci], 0, 0, 0);
            acc[ci] = __builtin_amdgcn_mfma_f32_16x16x32_bf16(al, bh, acc[ci], 0, 0, 0);
            acc[ci] = __builtin_amdgcn_mfma_f32_16x16x32_bf16(ah, bl, acc[ci], 0, 0, 0);
        }
        if (t + 1 < NT) {
            *(uint4*)&Bh[cbuf ^ 1][tid * 8] = sbh0;
            *(uint4*)&Bh[cbuf ^ 1][2048 + tid * 8] = sbh1;
            *(uint4*)&Bl[cbuf ^ 1][tid * 8] = sbl0;
            *(uint4*)&Bl[cbuf ^ 1][2048 + tid * 8] = sbl1;
            ac0 = an0;  ac1 = an1;
        }
        __syncthreads();
    }

    float cbv[8];
#pragma unroll
    for (int ci = 0; ci < 8; ++ci) cbv[ci] = cb[ci * 16 + fr];
#pragma unroll
    for (int j = 0; j < 4; ++j) {
        int row = i0 + kg * 4 + j;
        if (row < N) {
            float scv = cs[row];
#pragma unroll
            for (int ci = 0; ci < 8; ++ci) {
                h1[(size_t)row * 128 + ci * 16 + fr] =
                    f2bf(scv * (acc[ci][j] + cbv[ci]));
            }
        }
    }
}

// Layer-1 aggregation: 16-lane group per node (uint4 = 8 bf16 cols per
// lane), unroll 8; 4 nodes per wave in flight.
__global__ __launch_bounds__(256) void k_agg1(
    const unsigned short* __restrict__ h1, const int* __restrict__ rowp,
    const int* __restrict__ csr, const float* __restrict__ cd,
    const float* __restrict__ b1, float* __restrict__ y, int N)
{
    int i = blockIdx.x * 16 + (threadIdx.x >> 4);
    if (i >= N) return;
    int lane = threadIdx.x & 15;
    int s0 = rowp[i], s1 = rowp[i + 1];
    float a0 = 0.f, a1 = 0.f, a2 = 0.f, a3 = 0.f;
    float a4 = 0.f, a5 = 0.f, a6 = 0.f, a7 = 0.f;
#define AGG1_ACC(v)                                                       \
    a0 += __uint_as_float((v).x << 16);                                   \
    a1 += __uint_as_float((v).x & 0xffff0000u);                           \
    a2 += __uint_as_float((v).y << 16);                                   \
    a3 += __uint_as_float((v).y & 0xffff0000u);                           \
    a4 += __uint_as_float((v).z << 16);                                   \
    a5 += __uint_as_float((v).z & 0xffff0000u);                           \
    a6 += __uint_as_float((v).w << 16);                                   \
    a7 += __uint_as_float((v).w & 0xffff0000u);
    int e = s0;
    for (; e + 8 <= s1; e += 8) {
        uint4 v0 = *(const uint4*)(h1 + (size_t)csr[e + 0] * 128 + lane * 8);
        uint4 v1 = *(const uint4*)(h1 + (size_t)csr[e + 1] * 128 + lane * 8);
        uint4 v2 = *(const uint4*)(h1 + (size_t)csr[e + 2] * 128 + lane * 8);
        uint4 v3 = *(const uint4*)(h1 + (size_t)csr[e + 3] * 128 + lane * 8);
        uint4 v4 = *(const uint4*)(h1 + (size_t)csr[e + 4] * 128 + lane * 8);
        uint4 v5 = *(const uint4*)(h1 + (size_t)csr[e + 5] * 128 + lane * 8);
        uint4 v6 = *(const uint4*)(h1 + (size_t)csr[e + 6] * 128 + lane * 8);
        uint4 v7 = *(const uint4*)(h1 + (size_t)csr[e + 7] * 128 + lane * 8);
        AGG1_ACC(v0) AGG1_ACC(v1) AGG1_ACC(v2) AGG1_ACC(v3)
        AGG1_ACC(v4) AGG1_ACC(v5) AGG1_ACC(v6) AGG1_ACC(v7)
    }
    for (; e < s1; ++e) {
        uint4 v = *(const uint4*)(h1 + (size_t)csr[e] * 128 + lane * 8);
        AGG1_ACC(v)
    }
#undef AGG1_ACC
    float cdi = cd[i];
    float4 bv0 = *(const float4*)(b1 + lane * 8);
    float4 bv1 = *(const float4*)(b1 + lane * 8 + 4);
    float4 o0, o1;
    o0.x = fmaxf(fmaf(a0, cdi, bv0.x), 0.f);
    o0.y = fmaxf(fmaf(a1, cdi, bv0.y), 0.f);
    o0.z = fmaxf(fmaf(a2, cdi, bv0.z), 0.f);
    o0.w = fmaxf(fmaf(a3, cdi, bv0.w), 0.f);
    o1.x = fmaxf(fmaf(a4, cdi, bv1.x), 0.f);
    o1.y = fmaxf(fmaf(a5, cdi, bv1.y), 0.f);
    o1.z = fmaxf(fmaf(a6, cdi, bv1.z), 0.f);
    o1.w = fmaxf(fmaf(a7, cdi, bv1.w), 0.f);
    *(float4*)(y + (size_t)i * 128 + lane * 8) = o0;
    *(float4*)(y + (size_t)i * 128 + lane * 8 + 4) = o1;
}

// ---- k_h2 (unchanged): A direct; fragment-order B2 (32KB) staged once.
__global__ __launch_bounds__(256, 3) void k_h2(
    const float* __restrict__ y,
    const unsigned short* __restrict__ w2tf_hi, const unsigned short* __restrict__ w2tf_lo,
    const float* __restrict__ cs, unsigned short* __restrict__ h2, int N)
{
    constexpr int NT = 4;
    __shared__ __align__(16) short B2h[8192];
    __shared__ __align__(16) short B2l[8192];
    int tid = threadIdx.x;
    int lane = tid & 63, w = tid >> 6;
    int fr = lane & 15, kg = lane >> 4;
    int i0 = blockIdx.x * 128 + w * 32;
    int r0 = i0 + fr;       if (r0 >= N) r0 = N - 1;
    int r1 = i0 + 16 + fr;  if (r1 >= N) r1 = N - 1;
    const float* a0 = y + (size_t)r0 * 128 + kg * 8;
    const float* a1 = y + (size_t)r1 * 128 + kg * 8;

#pragma unroll
    for (int i = 0; i < 4; ++i) {
        *(uint4*)&B2h[(i * 256 + tid) * 8] = *(const uint4*)(w2tf_hi + (size_t)(i * 256 + tid) * 8);
        *(uint4*)&B2l[(i * 256 + tid) * 8] = *(const uint4*)(w2tf_lo + (size_t)(i * 256 + tid) * 8);
    }
    __syncthreads();

    f32x4 acc[2][4];
#pragma unroll
    for (int ri = 0; ri < 2; ++ri)
#pragma unroll
        for (int ci = 0; ci < 4; ++ci) acc[ri][ci] = (f32x4)0.f;

    float4 ar00 = *(const float4*)(a0);
    float4 ar01 = *(const float4*)(a0 + 4);
    float4 ar10 = *(const float4*)(a1);
    float4 ar11 = *(const float4*)(a1 + 4);

    for (int t = 0; t < NT; ++t) {
        short8 ah0, al0, ah1, al1;
        split_f4(ar00, ar01, ah0, al0);
        split_f4(ar10, ar11, ah1, al1);
        if (t + 1 < NT) {
            ar00 = *(const float4*)(a0 + (t + 1) * 32);
            ar01 = *(const float4*)(a0 + (t + 1) * 32 + 4);
            ar10 = *(const float4*)(a1 + (t + 1) * 32);
            ar11 = *(const float4*)(a1 + (t + 1) * 32 + 4);
        }
#pragma unroll
        for (int ci = 0; ci < 4; ++ci) {
            short8 bh = *(const short8*)&B2h[((t * 4 + ci) * 64 + lane) * 8];
            short8 bl = *(const short8*)&B2l[((t * 4 + ci) * 64 + lane) * 8];
            acc[0][ci] = __builtin_amdgcn_mfma_f32_16x16x32_bf16(ah0, bh, acc[0][ci], 0, 0, 0);
            acc[0][ci] = __builtin_amdgcn_mfma_f32_16x16x32_bf16(al0, bh, acc[0][ci], 0, 0, 0);
            acc[0][ci] = __builtin_amdgcn_mfma_f32_16x16x32_bf16(ah0, bl, acc[0][ci], 0, 0, 0);
            acc[1][ci] = __builtin_amdgcn_mfma_f32_16x16x32_bf16(ah1, bh, acc[1][ci], 0, 0, 0);
            acc[1][ci] = __builtin_amdgcn_mfma_f32_16x16x32_bf16(al1, bh, acc[1][ci], 0, 0, 0);
            acc[1][ci] = __builtin_amdgcn_mfma_f32_16x16x32_bf16(ah1, bl, acc[1][ci], 0, 0, 0);
        }
    }

#pragma unroll
    for (int ri = 0; ri < 2; ++ri) {
#pragma unroll
        for (int j = 0; j < 4; ++j) {
            int row = i0 + ri * 16 + kg * 4 + j;
            if (row < N) {
                float scv = cs[row];
#pragma unroll
                for (int ci = 0; ci < 4; ++ci) {
                    h2[(size_t)row * 64 + ci * 16 + fr] = f2bf(scv * acc[ri][ci][j]);
                }
            }
        }
    }
}

// Layer-2 aggregation: 16-lane group per node (uint2 = 4 bf16 cols/lane).
__global__ __launch_bounds__(256) void k_agg2(
    const unsigned short* __restrict__ h2, const int* __restrict__ rowp,
    const int* __restrict__ csr, const float* __restrict__ cd,
    const float* __restrict__ b2, float* __restrict__ out, int N)
{
    int i = blockIdx.x * 16 + (threadIdx.x >> 4);
    if (i >= N) return;
    int lane = threadIdx.x & 15;
    int s0 = rowp[i], s1 = rowp[i + 1];
    float a0 = 0.f, a1 = 0.f, a2 = 0.f, a3 = 0.f;
#define AGG2_ACC(v)                                                       \
    a0 += __uint_as_float((v).x << 16);                                   \
    a1 += __uint_as_float((v).x & 0xffff0000u);                           \
    a2 += __uint_as_float((v).y << 16);                                   \
    a3 += __uint_as_float((v).y & 0xffff0000u);
    int e = s0;
    for (; e + 8 <= s1; e += 8) {
        uint2 v0 = *(const uint2*)(h2 + (size_t)csr[e + 0] * 64 + lane * 4);
        uint2 v1 = *(const uint2*)(h2 + (size_t)csr[e + 1] * 64 + lane * 4);
        uint2 v2 = *(const uint2*)(h2 + (size_t)csr[e + 2] * 64 + lane * 4);
        uint2 v3 = *(const uint2*)(h2 + (size_t)csr[e + 3] * 64 + lane * 4);
        uint2 v4 = *(const uint2*)(h2 + (size_t)csr[e + 4] * 64 + lane * 4);
        uint2 v5 = *(const uint2*)(h2 + (size_t)csr[e + 5] * 64 + lane * 4);
        uint2 v6 = *(const uint2*)(h2 + (size_t)csr[e + 6] * 64 + lane * 4);
        uint2 v7 = *(const uint2*)(h2 + (size_t)csr[e + 7] * 64 + lane * 4);
        AGG2_ACC(v0) AGG2_ACC(v1) AGG2_ACC(v2) AGG2_ACC(v3)
        AGG2_ACC(v4) AGG2_ACC(v5) AGG2_ACC(v6) AGG2_ACC(v7)
    }
    for (; e < s1; ++e) {
        uint2 v = *(const uint2*)(h2 + (size_t)csr[e] * 64 + lane * 4);
        AGG2_ACC(v)
    }
#undef AGG2_ACC
    float cdi = cd[i];
    float4 bv = *(const float4*)(b2 + lane * 4);
    float4 o;
    o.x = fmaf(a0, cdi, bv.x);
    o.y = fmaf(a1, cdi, bv.y);
    o.z = fmaf(a2, cdi, bv.z);
    o.w = fmaf(a3, cdi, bv.w);
    *(float4*)(out + (size_t)i * 64 + lane * 4) = o;
}

extern "C" void kernel_launch(void* const* d_in, const int* in_sizes, int n_in,
                              void* d_out, int out_size, void* d_ws, size_t ws_size,
                              hipStream_t stream)
{
    const int* src = (const int*)d_in[0];
    const int* dst = (const int*)d_in[1];
    const float* logits = (const float*)d_in[2];
    const float* features = (const float*)d_in[3];
    const float* projW = (const float*)d_in[4];
    const float* projb = (const float*)d_in[5];
    const float* deg_table = (const float*)d_in[6];
    const float* W1 = (const float*)d_in[7];
    const float* b1 = (const float*)d_in[8];
    const float* W2 = (const float*)d_in[9];
    const float* b2 = (const float*)d_in[10];
    const int E = in_sizes[0];
    const int N = in_sizes[2] / 64;

    char* base = (char*)d_ws;
    size_t off = 0;
    auto alloc = [&](size_t bytes) -> void* {
        void* p = base + off;
        off += (bytes + 255) & ~(size_t)255;
        return p;
    };
    int* ind    = (int*)alloc((size_t)N * 4);
    int* rowp   = (int*)alloc((size_t)(N + 1) * 4);
    int* csr    = (int*)alloc((size_t)E * 4);
    unsigned* ebuf = (unsigned*)alloc((size_t)E * 4);
    unsigned short* sbuf = (unsigned short*)alloc((size_t)E * 2);
    int* didx   = (int*)alloc((size_t)N * 4);
    float* cs   = (float*)alloc((size_t)N * 4);
    float* cd   = (float*)alloc((size_t)N * 4);
    float* WF   = (float*)alloc((size_t)512 * 128 * 4);
    float* cb   = (float*)alloc((size_t)128 * 4);
    int* dcount = (int*)alloc(128 * 4);
    int* scount = (int*)alloc(128 * 4);
    int* dboff  = (int*)alloc(128 * 4);
    int* sboff  = (int*)alloc(128 * 4);
    int* dcur   = (int*)alloc(128 * 4);
    int* scur   = (int*)alloc(128 * 4);
    unsigned short* wtf_hi  = (unsigned short*)alloc((size_t)81920 * 2);
    unsigned short* wtf_lo  = (unsigned short*)alloc((size_t)81920 * 2);
    unsigned short* w2tf_hi = (unsigned short*)alloc((size_t)8192 * 2);
    unsigned short* w2tf_lo = (unsigned short*)alloc((size_t)8192 * 2);
    unsigned short* h1 = (unsigned short*)alloc((size_t)N * 128 * 2);
    float* yb   = (float*)alloc((size_t)N * 128 * 4);
    unsigned short* h2 = h1;   // h1 dead after k_agg1; reuse
    float* outp = (float*)d_out;

    hipMemsetAsync(dcount, 0, 128 * 4, stream);
    hipMemsetAsync(scount, 0, 128 * 4, stream);

    int mb1 = (N + 63) / 64;
    int mb2 = (N + 127) / 128;
    int ebk = (E + 4095) / 4096;
    int nbuck = (N + 1023) / 1024;   // <=128 for N<=131072

    k_bcount<<<ebk, 256, 0, stream>>>(src, dst, E, dcount, scount);
    k_bscan<<<1, 128, 0, stream>>>(dcount, scount, nbuck, E, dboff, sboff, dcur, scur, rowp, N);
    k_scatter2<<<ebk, 256, 0, stream>>>(src, dst, E, dcur, scur, ebuf, sbuf, nbuck);
    k_bucket_dst<<<nbuck, 512, 0, stream>>>(ebuf, dboff, dcount, ind, rowp, csr, N);
    k_bucket_src<<<nbuck, 512, 0, stream>>>(sbuf, sboff, scount, ind, cs, cd, didx, N);
    k_wf<<<257, 256, 0, stream>>>(projW, projb, W1, WF, cb);
    k_wt<<<352, 256, 0, stream>>>(WF, W1, W2, wtf_hi, wtf_lo, w2tf_hi, w2tf_lo);
    k_h1<<<mb1, 256, 0, stream>>>(logits, features, deg_table, didx, wtf_hi, wtf_lo, cb, cs, h1, N);
    k_agg1<<<(N + 15) / 16, 256, 0, stream>>>(h1, rowp, csr, cd, b1, yb, N);
    k_h2<<<mb2, 256, 0, stream>>>(yb, w2tf_hi, w2tf_lo, cs, h2, N);
    k_agg2<<<(N + 15) / 16, 256, 0, stream>>>(h2, rowp, csr, cd, b2, outp, N);
}